// Round 8
// baseline (210.903 us; speedup 1.0000x reference)
//
#include <hip/hip_runtime.h>
#include <hip/hip_bf16.h>
#include <math.h>

#define BZ 16
#define NN 1024
#define FF 1024
#define ALPHA 0.2f
#define NEG_INF (-9e15f)

typedef __bf16 bf16x8 __attribute__((ext_vector_type(8)));
typedef __bf16 bf16x4 __attribute__((ext_vector_type(4)));
typedef float  f32x4  __attribute__((ext_vector_type(4)));
typedef int    i32x4  __attribute__((ext_vector_type(4)));

#define GLOBAL_AS __attribute__((address_space(1)))
#define LDS_AS    __attribute__((address_space(3)))

__device__ inline void load_lds16(const void* g, void* l) {
    __builtin_amdgcn_global_load_lds((const GLOBAL_AS void*)g, (LDS_AS void*)l, 16, 0, 0);
}

// nt stores only on streaming producer outputs (R7: helped ~20us there;
// hurt the GEMM epilogue, so GEMM stores are plain).
__device__ inline void nt_store64(void* p, const void* v) {
    __builtin_nontemporal_store(*(const unsigned long long*)v, (unsigned long long*)p);
}

__device__ inline float waveAllSum(float v) {
    for (int o = 32; o; o >>= 1) v += __shfl_xor(v, o);
    return v;
}
__device__ inline float waveAllMax(float v) {
    for (int o = 32; o; o >>= 1) v = fmaxf(v, __shfl_xor(v, o));
    return v;
}
__device__ inline float waveReduceSum(float v) {
    for (int o = 32; o; o >>= 1) v += __shfl_down(v, o);
    return v;
}
__device__ inline float dot4(f32x4 a, f32x4 b) {
    return a.x * b.x + a.y * b.y + a.z * b.z + a.w * b.w;
}

// ===========================================================================
// 256x256 bf16 MFMA GEMM, BK=32, 4 LDS buffers, 1 phase per K-tile.
// C = A @ Bt^T.  A [16384][1024] bf16 row-major; Bt [1024][1024] bf16
// row-major (batch stride sB; 0 = shared).
// 8 waves (2x4), 512 thr. LDS 128KB: A bufs [0,64K), B bufs [64K,128K),
// each buf = [256 rows][32 k] bf16 = 16KB, linear (64B rows -> fragment
// reads are contiguous 1KB blocks: conflict-free, NO swizzle needed).
// Per phase: 4 gload_lds (stage tile t+3) + 12 ds_read_b128 + 32 MFMA,
// 2 barriers, vmcnt(8) (phase t confirms tile t+1; prefetch depth 3).
// EPI==1: fp32 + elu, row-major.  EPI==2: bf16 transposed per batch (C^T).
// ===========================================================================
template<int EPI>
__global__ __launch_bounds__(512, 2) void gemm256(
    const __bf16* __restrict__ A, const __bf16* __restrict__ Bt,
    float* __restrict__ Cf, __bf16* __restrict__ Ct, size_t sB)
{
    __shared__ char lds[131072];

    // bijective XCD swizzle (nwg = 256, divisible by 8)
    const int bid = blockIdx.x;
    const int l   = (bid & 7) * 32 + (bid >> 3);
    const int tileM = (l >> 2) * 256;          // 64 M-tiles
    const int tileN = (l & 3) * 256;           // 4 N-tiles

    const int tid = threadIdx.x, lane = tid & 63, wid = tid >> 6;
    const int wr = wid >> 2, wc = wid & 3;     // 2 x 4 waves

    const int batch = tileM >> 10;
    const char* Ab  = (const char*)(A + (size_t)tileM * FF);
    const char* Bbp = (const char*)(Bt + (size_t)batch * sB + (size_t)tileN * FF);

    // staging map (linear, no swizzle): thread tid covers LDS byte tid*16 of
    // the 8KB half-buf; global row = tid>>2, col-byte = (tid&3)*16.
    const size_t srowoff = (size_t)(tid >> 2) * 2048 + (size_t)(tid & 3) * 16;

#define STAGEA(buf, kt) do {                                                  \
    const char* g_ = Ab + srowoff + (size_t)(kt) * 64;                        \
    load_lds16(g_,              lds + (buf) * 16384 + wid * 1024);            \
    load_lds16(g_ + 128 * 2048, lds + (buf) * 16384 + 8192 + wid * 1024);     \
} while (0)
#define STAGEB(buf, kt) do {                                                  \
    const char* g_ = Bbp + srowoff + (size_t)(kt) * 64;                       \
    load_lds16(g_,              lds + 65536 + (buf) * 16384 + wid * 1024);    \
    load_lds16(g_ + 128 * 2048, lds + 65536 + (buf) * 16384 + 8192 + wid * 1024);\
} while (0)

    // fragment read addressing: frag = 16 consecutive 64B rows = 1KB block
    const int fr = lane & 15, kq = lane >> 4;
    const int aoff = (wr * 128 + fr) * 64 + kq * 16;
    const int boff = (wc * 64 + fr) * 64 + kq * 16;

#define RD(off) (*(const bf16x8*)(lds + (off)))
#define BAR   __builtin_amdgcn_s_barrier()
#define LGKM0 do { asm volatile("s_waitcnt lgkmcnt(0)" ::: "memory");        \
                   __builtin_amdgcn_sched_barrier(0); } while (0)
#define VM8   asm volatile("s_waitcnt vmcnt(8)" ::: "memory")
#define VM0   asm volatile("s_waitcnt vmcnt(0)" ::: "memory")
#define PRIO1 __builtin_amdgcn_s_setprio(1)
#define PRIO0 __builtin_amdgcn_s_setprio(0)

    f32x4 acc[8][4];
    #pragma unroll
    for (int m = 0; m < 8; ++m)
        #pragma unroll
        for (int n = 0; n < 4; ++n) acc[m][n] = (f32x4){0.f, 0.f, 0.f, 0.f};

    bf16x8 a[8], b[4];

    // prologue: stage tiles 0,1,2 (12 loads/wave); confirm tile 0
    STAGEA(0, 0); STAGEB(0, 0);
    STAGEA(1, 1); STAGEB(1, 1);
    STAGEA(2, 2); STAGEB(2, 2);
    VM8; BAR;

    const int NT = FF / 32;   // 32 K-tiles
    #pragma unroll 4
    for (int t = 0; t < NT; ++t) {
        const int cur = t & 3;
        // stage tile t+3 (clamped tail re-stages tile 31 into unread bufs)
        const int kt = (t + 3 < NT) ? t + 3 : NT - 1;
        const int nb = (t + 3) & 3;
        STAGEA(nb, kt); STAGEB(nb, kt);
        // ds_read 12 frags from buf[cur]
        #pragma unroll
        for (int m = 0; m < 8; ++m) a[m] = RD(cur * 16384 + aoff + m * 1024);
        #pragma unroll
        for (int n = 0; n < 4; ++n) b[n] = RD(65536 + cur * 16384 + boff + n * 1024);
        BAR; LGKM0; PRIO1;
        #pragma unroll
        for (int n = 0; n < 4; ++n)
            #pragma unroll
            for (int m = 0; m < 8; ++m)
                acc[m][n] = __builtin_amdgcn_mfma_f32_16x16x32_bf16(
                    a[m], b[n], acc[m][n], 0, 0, 0);
        PRIO0; VM8; BAR;
    }

    // ---- epilogue (plain stores) ----
    if (EPI == 1) {
        #pragma unroll
        for (int fm = 0; fm < 8; ++fm) {
            const int row0 = tileM + wr * 128 + fm * 16 + kq * 4;
            #pragma unroll
            for (int fn = 0; fn < 4; ++fn) {
                const int col = tileN + wc * 64 + fn * 16 + fr;
                #pragma unroll
                for (int r = 0; r < 4; ++r) {
                    float v = acc[fm][fn][r];
                    v = (v > 0.f) ? v : expm1f(v);
                    Cf[(size_t)(row0 + r) * FF + col] = v;
                }
            }
        }
    } else {
        // write C^T bf16 per batch: stage per-wave 128x64 tile into LDS
        VM0; BAR;   // drain tail gloads; all LDS reads finished
        char* wlds = lds + wid * 16384;   // [64 c][128 r] bf16, swizzled
        #pragma unroll
        for (int fm = 0; fm < 8; ++fm)
            #pragma unroll
            for (int fn = 0; fn < 4; ++fn) {
                const int ccol = fn * 16 + fr;
                const int crow = fm * 16 + kq * 4;
                int addr = (ccol * 256 + crow * 2) ^ ((ccol & 7) << 4);
                bf16x4 v = { (__bf16)acc[fm][fn][0], (__bf16)acc[fm][fn][1],
                             (__bf16)acc[fm][fn][2], (__bf16)acc[fm][fn][3] };
                *(bf16x4*)(wlds + addr) = v;
            }
        const int jb = (tileM & 1023) + wr * 128;
        __bf16* Wt = Ct + (size_t)batch * (1024 * 1024);
        #pragma unroll
        for (int pass = 0; pass < 16; ++pass) {
            const int fl  = pass * 4 + (lane >> 4);   // 0..63 (c-dim)
            const int jby = (lane & 15) * 16;         // byte offset in j-dim
            int addr = (fl * 256 + jby) ^ ((fl & 7) << 4);
            bf16x8 v = *(const bf16x8*)(wlds + addr);
            const int fg = tileN + wc * 64 + fl;
            *(bf16x8*)((char*)(Wt + (size_t)fg * 1024 + jb) + jby) = v;
        }
    }
#undef STAGEA
#undef STAGEB
#undef RD
}

// ---------------------------------------------------------------------------
// scores_h: wave-per-row. Emits h_bf (nt) + d0..d3.
// ---------------------------------------------------------------------------
__global__ __launch_bounds__(256) void scores_h(
    const float* __restrict__ h, const float* __restrict__ wa,
    __bf16* __restrict__ h_bf,
    float* __restrict__ sSrcSS, float* __restrict__ pD1,
    float* __restrict__ sSrcDS, float* __restrict__ pD3)
{
    const int wid = threadIdx.x >> 6, lane = threadIdx.x & 63;
    const int row = blockIdx.x * 4 + wid;
    const f32x4* hr  = (const f32x4*)(h + (size_t)row * FF);
    const f32x4* w0p = (const f32x4*)wa;
    const f32x4* w1p = (const f32x4*)(wa + FF);
    const f32x4* w2p = (const f32x4*)(wa + 2 * FF);
    const f32x4* w3p = (const f32x4*)(wa + 3 * FF);

    f32x4 hv[4], w0[4], w1[4], w2[4], w3[4];
    #pragma unroll
    for (int q = 0; q < 4; ++q) hv[q] = hr[q * 64 + lane];
    #pragma unroll
    for (int q = 0; q < 4; ++q) {
        const int i = q * 64 + lane;
        w0[q] = w0p[i]; w1[q] = w1p[i]; w2[q] = w2p[i]; w3[q] = w3p[i];
    }

    bf16x4* hbp = (bf16x4*)(h_bf + (size_t)row * FF);
    #pragma unroll
    for (int q = 0; q < 4; ++q) {
        f32x4 v = hv[q];
        bf16x4 hb = { (__bf16)v.x, (__bf16)v.y, (__bf16)v.z, (__bf16)v.w };
        nt_store64(&hbp[q * 64 + lane], &hb);
    }

    float d0 = 0.f, d1 = 0.f, d2 = 0.f, d3 = 0.f;
    #pragma unroll
    for (int q = 0; q < 4; ++q) {
        d0 += dot4(hv[q], w0[q]);
        d1 += dot4(hv[q], w1[q]);
        d2 += dot4(hv[q], w2[q]);
        d3 += dot4(hv[q], w3[q]);
    }
    d0 = waveAllSum(d0); d1 = waveAllSum(d1);
    d2 = waveAllSum(d2); d3 = waveAllSum(d3);
    if (lane == 0) {
        sSrcSS[row] = d0;
        pD1[row]    = d1;
        sSrcDS[row] = d2;
        pD3[row]    = d3;
    }
}

// ---------------------------------------------------------------------------
// scores_react: wave-per-row. Emits d4 (hx.vSS), d5 (ho.vDS).
// ---------------------------------------------------------------------------
__global__ __launch_bounds__(256) void scores_react(
    const float* __restrict__ hx, const float* __restrict__ ho,
    const float* __restrict__ vSS, const float* __restrict__ vDS,
    float* __restrict__ pD4, float* __restrict__ pD5)
{
    const int wid = threadIdx.x >> 6, lane = threadIdx.x & 63;
    const int row = blockIdx.x * 4 + wid;
    const f32x4* xr  = (const f32x4*)(hx + (size_t)row * FF);
    const f32x4* orr = (const f32x4*)(ho + (size_t)row * FF);
    const f32x4* vsp = (const f32x4*)vSS;
    const f32x4* vdp = (const f32x4*)vDS;

    f32x4 xv[4], ov[4], vs[4], vd[4];
    #pragma unroll
    for (int q = 0; q < 4; ++q) {
        const int i = q * 64 + lane;
        xv[q] = xr[i]; ov[q] = orr[i];
    }
    #pragma unroll
    for (int q = 0; q < 4; ++q) {
        const int i = q * 64 + lane;
        vs[q] = vsp[i]; vd[q] = vdp[i];
    }

    float d4 = 0.f, d5 = 0.f;
    #pragma unroll
    for (int q = 0; q < 4; ++q) {
        d4 += dot4(xv[q], vs[q]);
        d5 += dot4(ov[q], vd[q]);
    }
    d4 = waveAllSum(d4); d5 = waveAllSum(d5);
    if (lane == 0) {
        pD4[row] = d4;
        pD5[row] = d5;
    }
}

// Transpose + convert: in [R][C] fp32 -> out [C][R] bf16 (W only), nt stores.
__global__ __launch_bounds__(256) void transpose_cvt(
    const float* __restrict__ in, __bf16* __restrict__ out, int R, int C)
{
    const float* ib = in;
    __bf16* ob = out;
    const int r0 = blockIdx.y * 64;
    const int c0 = blockIdx.x * 64;
    __shared__ __bf16 t[64][66];
    #pragma unroll
    for (int it = 0; it < 16; ++it) {
        int idx = threadIdx.x + it * 256;
        int r = idx >> 6, c = idx & 63;
        t[r][c] = (__bf16)ib[(size_t)(r0 + r) * C + c0 + c];
    }
    __syncthreads();
    #pragma unroll
    for (int it = 0; it < 4; ++it) {
        int idx = threadIdx.x + it * 256;
        int rr = idx >> 4;
        int cc = (idx & 15) * 4;
        bf16x4 v = { t[cc][rr], t[cc + 1][rr], t[cc + 2][rr], t[cc + 3][rr] };
        nt_store64(&ob[(size_t)(c0 + rr) * R + r0 + cc], &v);
    }
}

// wa[q][i]: wa_q = W @ a_q (row dots).
__global__ __launch_bounds__(256) void prep_wa(
    const float* __restrict__ W, const float* __restrict__ aSS,
    const float* __restrict__ aDS, float* __restrict__ wa)
{
    const int i = blockIdx.x;
    const int t = threadIdx.x;
    float4 w  = ((const float4*)(W + (size_t)i * FF))[t];
    float4 s1 = ((const float4*)aSS)[t];
    float4 s2 = ((const float4*)(aSS + FF))[t];
    float4 d1 = ((const float4*)aDS)[t];
    float4 d2 = ((const float4*)(aDS + FF))[t];
    float v0 = w.x * s1.x + w.y * s1.y + w.z * s1.z + w.w * s1.w;
    float v1 = w.x * s2.x + w.y * s2.y + w.z * s2.z + w.w * s2.w;
    float v2 = w.x * d1.x + w.y * d1.y + w.z * d1.z + w.w * d1.w;
    float v3 = w.x * d2.x + w.y * d2.y + w.z * d2.z + w.w * d2.w;
    v0 = waveReduceSum(v0); v1 = waveReduceSum(v1);
    v2 = waveReduceSum(v2); v3 = waveReduceSum(v3);
    __shared__ float red[4][4];
    int wid = t >> 6;
    if ((t & 63) == 0) { red[wid][0] = v0; red[wid][1] = v1; red[wid][2] = v2; red[wid][3] = v3; }
    __syncthreads();
    if (t < 4) {
        float s = red[0][t] + red[1][t] + red[2][t] + red[3][t];
        wa[(size_t)t * FF + i] = s;
    }
}

// v = csk_W^T @ a2 for SS and DS.
__global__ __launch_bounds__(256) void prep_v(
    const float* __restrict__ cskW, const float* __restrict__ aSS,
    const float* __restrict__ aDS, float* __restrict__ vSS, float* __restrict__ vDS)
{
    const int g0 = blockIdx.x * 64;
    const int gl = threadIdx.x & 63;
    const int fs = threadIdx.x >> 6;
    const int g = g0 + gl;
    float aS = 0.f, aD = 0.f;
    for (int f = fs * 256; f < fs * 256 + 256; ++f) {
        float w = cskW[(size_t)f * FF + g];
        aS += w * aSS[FF + f];
        aD += w * aDS[FF + f];
    }
    __shared__ float rS[4][64], rD[4][64];
    rS[fs][gl] = aS; rD[fs][gl] = aD;
    __syncthreads();
    if (fs == 0) {
        vSS[g] = rS[0][gl] + rS[1][gl] + rS[2][gl] + rS[3][gl];
        vDS[g] = rD[0][gl] + rD[1][gl] + rD[2][gl] + rD[3][gl];
    }
}

__global__ __launch_bounds__(256) void prep_c(
    const float* __restrict__ cskb, const float* __restrict__ aSS,
    const float* __restrict__ aDS, float* __restrict__ cv)
{
    int t = threadIdx.x;
    float cS = 0.f, cD = 0.f;
    for (int f = t; f < FF; f += 256) {
        float bb = cskb[f];
        cS += bb * aSS[FF + f];
        cD += bb * aDS[FF + f];
    }
    cS = waveReduceSum(cS);
    cD = waveReduceSum(cD);
    __shared__ float rA[4], rB[4];
    int wid = t >> 6;
    if ((t & 63) == 0) { rA[wid] = cS; rB[wid] = cD; }
    __syncthreads();
    if (t == 0) {
        cv[0] = rA[0] + rA[1] + rA[2] + rA[3];
        cv[1] = rB[0] + rB[1] + rB[2] + rB[3];
    }
}

// ---------------------------------------------------------------------------
// Row softmax -> att (bf16, nt stores), wave-per-row.
// ---------------------------------------------------------------------------
__global__ __launch_bounds__(256) void softmax_att(
    const float* __restrict__ mx, const float* __restrict__ mo,
    const float* __restrict__ sSrcSS, const float* __restrict__ sSrcDS,
    const float* __restrict__ pD1, const float* __restrict__ pD3,
    const float* __restrict__ pD4, const float* __restrict__ pD5,
    const float* __restrict__ cv, __bf16* __restrict__ att)
{
    const int wid = threadIdx.x >> 6, lane = threadIdx.x & 63;
    const int row = blockIdx.x * 4 + wid;
    const int base = row & ~(NN - 1);
    const float srcS = sSrcSS[row];
    const float srcD = sSrcDS[row];
    const float cv0 = cv[0], cv1 = cv[1];
    const f32x4* mxr = (const f32x4*)(mx + (size_t)row * NN);
    const f32x4* mor = (const f32x4*)(mo + (size_t)row * NN);
    const f32x4* p1p = (const f32x4*)(pD1 + base);
    const f32x4* p3p = (const f32x4*)(pD3 + base);
    const f32x4* p4p = (const f32x4*)(pD4 + base);
    const f32x4* p5p = (const f32x4*)(pD5 + base);

    float ev[16];
    float m = -INFINITY;
    #pragma unroll
    for (int q = 0; q < 4; ++q) {
        const int idx = q * 64 + lane;
        f32x4 a = mxr[idx], o = mor[idx];
        f32x4 p1 = p1p[idx], p3 = p3p[idx], p4 = p4p[idx], p5 = p5p[idx];
        #pragma unroll
        for (int l = 0; l < 4; ++l) {
            float eS = srcS + p1[l] + p4[l] + cv0;
            float lS = (eS >= 0.f) ? eS : ALPHA * eS;
            float eD = srcD + p3[l] + p5[l] + cv1;
            float lD = (eD >= 0.f) ? eD : ALPHA * eD;
            float val = (a[l] > 0.f) ? (lS * a[l] + lD * o[l]) : NEG_INF;
            ev[q * 4 + l] = val;
            m = fmaxf(m, val);
        }
    }
    m = waveAllMax(m);

    float s = 0.f;
    #pragma unroll
    for (int i = 0; i < 16; ++i) {
        float p = expf(ev[i] - m);
        ev[i] = p;
        s += p;
    }
    s = waveAllSum(s);
    const float inv = 1.f / s;

    bf16x4* ar = (bf16x4*)(att + (size_t)row * NN);
    #pragma unroll
    for (int q = 0; q < 4; ++q) {
        bf16x4 v = { (__bf16)(ev[q * 4 + 0] * inv), (__bf16)(ev[q * 4 + 1] * inv),
                     (__bf16)(ev[q * 4 + 2] * inv), (__bf16)(ev[q * 4 + 3] * inv) };
        nt_store64(&ar[q * 64 + lane], &v);
    }
}

// ---------------------------------------------------------------------------
extern "C" void kernel_launch(void* const* d_in, const int* in_sizes, int n_in,
                              void* d_out, int out_size, void* d_ws, size_t ws_size,
                              hipStream_t stream)
{
    const float* h    = (const float*)d_in[0];
    const float* hx   = (const float*)d_in[1];
    const float* ho   = (const float*)d_in[2];
    const float* mx   = (const float*)d_in[3];
    const float* mo   = (const float*)d_in[4];
    const float* W    = (const float*)d_in[5];
    const float* aSS  = (const float*)d_in[6];
    const float* aDS  = (const float*)d_in[7];
    const float* cskW = (const float*)d_in[8];
    const float* cskb = (const float*)d_in[9];
    float* out = (float*)d_out;

    char* ws = (char*)d_ws;
    const size_t MB = 1024 * 1024;
    __bf16* h_bf   = (__bf16*)ws;              // 32MB
    __bf16* WhT_bf = (__bf16*)(ws + 32 * MB);  // 32MB (per-batch [F][N] bf16)
    __bf16* att_bf = (__bf16*)(ws + 64 * MB);  // 32MB
    __bf16* WbfT   = (__bf16*)(ws + 96 * MB);  // 2MB
    float* wa     = (float*)(ws + 98 * MB);    // 16KB [4][FF]
    float* vSS    = wa + 4 * FF;
    float* vDS    = vSS + FF;
    float* cv     = vDS + FF;
    float* sSrcSS = cv + 64;
    float* sSrcDS = sSrcSS + BZ * NN;
    float* pD1    = sSrcDS + BZ * NN;
    float* pD3    = pD1 + BZ * NN;
    float* pD4    = pD3 + BZ * NN;
    float* pD5    = pD4 + BZ * NN;

    // 1) small prep (fp32)
    prep_wa<<<FF, 256, 0, stream>>>(W, aSS, aDS, wa);
    prep_v<<<16, 256, 0, stream>>>(cskW, aSS, aDS, vSS, vDS);
    prep_c<<<1, 256, 0, stream>>>(cskb, aSS, aDS, cv);
    // 2) W -> W^T bf16
    transpose_cvt<<<dim3(16, 16, 1), 256, 0, stream>>>(W, WbfT, FF, FF);
    // 3) score passes (stream-split, load-hoisted)
    scores_h<<<BZ * NN / 4, 256, 0, stream>>>(h, wa, h_bf, sSrcSS, pD1, sSrcDS, pD3);
    scores_react<<<BZ * NN / 4, 256, 0, stream>>>(hx, ho, vSS, vDS, pD4, pD5);
    // 4) Wh^T bf16 = (h @ W)^T per batch
    gemm256<2><<<256, 512, 0, stream>>>(h_bf, WbfT, nullptr, WhT_bf, 0);
    // 5) softmax -> att bf16
    softmax_att<<<BZ * NN / 4, 256, 0, stream>>>(mx, mo, sSrcSS, sSrcDS,
                                                 pD1, pD3, pD4, pD5, cv, att_bf);
    // 6) out = elu(att @ Wh)
    gemm256<1><<<256, 512, 0, stream>>>(att_bf, WhT_bf, out, nullptr,
                                        (size_t)NN * FF);
}

// Round 9
// 205.992 us; speedup vs baseline: 1.0238x; 1.0238x over previous
//
#include <hip/hip_runtime.h>
#include <hip/hip_bf16.h>
#include <math.h>

#define BZ 16
#define NN 1024
#define FF 1024
#define ALPHA 0.2f
#define NEG_INF (-9e15f)

typedef __bf16 bf16x8 __attribute__((ext_vector_type(8)));
typedef __bf16 bf16x4 __attribute__((ext_vector_type(4)));
typedef float  f32x4  __attribute__((ext_vector_type(4)));
typedef int    i32x4  __attribute__((ext_vector_type(4)));

#define GLOBAL_AS __attribute__((address_space(1)))
#define LDS_AS    __attribute__((address_space(3)))

__device__ inline void load_lds16(const void* g, void* l) {
    __builtin_amdgcn_global_load_lds((const GLOBAL_AS void*)g, (LDS_AS void*)l, 16, 0, 0);
}

// nt stores ONLY on streaming producer outputs (R7: +20us there; R7 also
// showed nt in the GEMM epilogue costs ~7us/gemm -> plain stores there).
__device__ inline void nt_store64(void* p, const void* v) {
    __builtin_nontemporal_store(*(const unsigned long long*)v, (unsigned long long*)p);
}

__device__ inline float waveAllSum(float v) {
    for (int o = 32; o; o >>= 1) v += __shfl_xor(v, o);
    return v;
}
__device__ inline float waveAllMax(float v) {
    for (int o = 32; o; o >>= 1) v = fmaxf(v, __shfl_xor(v, o));
    return v;
}
__device__ inline float waveReduceSum(float v) {
    for (int o = 32; o; o >>= 1) v += __shfl_down(v, o);
    return v;
}
__device__ inline float dot4(f32x4 a, f32x4 b) {
    return a.x * b.x + a.y * b.y + a.z * b.z + a.w * b.w;
}

// ===========================================================================
// 256x256 bf16 MFMA GEMM — R6's proven schedule (BK=64, 2 dbuf, 4 phases
// per K-tile, K-half split, st-swizzled LDS, counted vmcnt(4)).
// C = A @ Bt^T. A [16384][1024] bf16 rm; Bt [1024][1024] bf16 rm (batch
// stride sB; 0 = shared). 8 waves (2x4), 512 thr, 128KB LDS.
// EPI==1: fp32 + elu, row-major (plain stores).
// EPI==2: bf16 transposed per batch (C^T, plain stores).
// ===========================================================================
template<int EPI>
__global__ __launch_bounds__(512, 2) void gemm256(
    const __bf16* __restrict__ A, const __bf16* __restrict__ Bt,
    float* __restrict__ Cf, __bf16* __restrict__ Ct, size_t sB)
{
    __shared__ char lds[131072];

    // bijective XCD swizzle (nwg = 256, divisible by 8)
    const int bid = blockIdx.x;
    const int l   = (bid & 7) * 32 + (bid >> 3);
    const int tileM = (l >> 2) * 256;
    const int tileN = (l & 3) * 256;

    const int tid = threadIdx.x, lane = tid & 63, wid = tid >> 6;
    const int wr = wid >> 2, wc = wid & 3;

    const int batch = tileM >> 10;
    const char* Ab  = (const char*)(A + (size_t)tileM * FF);
    const char* Bbp = (const char*)(Bt + (size_t)batch * sB + (size_t)tileN * FF);

    // staging map: linear LDS dest, inverse-swizzled global source (rule #21)
    const int o1 = wid * 1024 + lane * 16;
    const int o2 = o1 + 8192;
    const int r1 = o1 >> 7, r2 = o2 >> 7;
    const size_t raoff1 = (size_t)r1 * 2048 + ((o1 & 127) ^ ((r1 & 7) << 4));
    const size_t raoff2 = (size_t)r2 * 2048 + ((o2 & 127) ^ ((r2 & 7) << 4));

#define STAGE(gb, ldsoff, half, kt) do {                                        \
    const char* g_ = (gb) + (size_t)(half) * (128 * 2048) + (size_t)(kt) * 128; \
    load_lds16(g_ + raoff1, lds + (ldsoff) + (half) * 16384 + wid * 1024);      \
    load_lds16(g_ + raoff2, lds + (ldsoff) + (half) * 16384 + 8192 + wid * 1024);\
} while (0)

    // fragment read addressing (swizzled)
    const int fr = lane & 15, kq = lane >> 4;
    const int fswz = (fr & 7) << 4;
    const int ck[2] = { (kq * 16) ^ fswz, (64 + kq * 16) ^ fswz };
    const int abase = (wr * 128 + fr) * 128;
    const int bbase = 32768 + (wc * 64 + fr) * 128;

#define RD(off) (*(const bf16x8*)(lds + (off)))
#define RDA(P, m, kh) RD((P) * 65536 + abase + (m) * 2048 + ck[kh])
#define RDB(P, n, kh) RD((P) * 65536 + bbase + (n) * 2048 + ck[kh])
#define MF16(amr, bvr, m0) do {                                              \
    _Pragma("unroll") for (int n = 0; n < 4; ++n)                            \
    _Pragma("unroll") for (int m = 0; m < 4; ++m)                            \
        acc[m0 + m][n] = __builtin_amdgcn_mfma_f32_16x16x32_bf16(            \
            amr[m], bvr[n], acc[m0 + m][n], 0, 0, 0); } while (0)
#define BAR   __builtin_amdgcn_s_barrier()
#define LGKM0 do { asm volatile("s_waitcnt lgkmcnt(0)" ::: "memory");        \
                   __builtin_amdgcn_sched_barrier(0); } while (0)
#define VM4   asm volatile("s_waitcnt vmcnt(4)" ::: "memory")
#define VM0   asm volatile("s_waitcnt vmcnt(0)" ::: "memory")
#define PRIO1 __builtin_amdgcn_s_setprio(1)
#define PRIO0 __builtin_amdgcn_s_setprio(0)

    f32x4 acc[8][4];
    #pragma unroll
    for (int m = 0; m < 8; ++m)
        #pragma unroll
        for (int n = 0; n < 4; ++n) acc[m][n] = (f32x4){0.f, 0.f, 0.f, 0.f};

    bf16x8 a0[4], a47k0[4], a47k1[4], b0[4], b1[4];

    STAGE(Ab,      0, 0, 0);  STAGE(Ab,      0, 1, 0);
    STAGE(Bbp, 32768, 0, 0);  STAGE(Bbp, 32768, 1, 0);
    STAGE(Bbp, 65536 + 32768, 0, 1);
    STAGE(Ab,  65536,         0, 1);
    VM4; BAR;

    const int NT = FF / 64;   // 16
    for (int it = 0; it < NT / 2; ++it) {
        const int t   = 2 * it;
        const int kt1 = t + 1;
        const int kt2 = (t + 2 < NT) ? t + 2 : NT - 1;
        const int kt3 = (t + 3 < NT) ? t + 3 : NT - 1;

        // ===== tile t (buf0) =====
        #pragma unroll
        for (int m = 0; m < 4; ++m) a0[m] = RDA(0, m, 0);
        #pragma unroll
        for (int n = 0; n < 4; ++n) b0[n] = RDB(0, n, 0);
        STAGE(Ab, 65536, 1, kt1);
        BAR; LGKM0; PRIO1; MF16(a0, b0, 0); PRIO0; BAR;

        #pragma unroll
        for (int m = 0; m < 4; ++m) a0[m] = RDA(0, m, 1);
        #pragma unroll
        for (int n = 0; n < 4; ++n) b1[n] = RDB(0, n, 1);
        STAGE(Bbp, 65536 + 32768, 1, kt1);
        BAR; LGKM0; PRIO1; MF16(a0, b1, 0); PRIO0; BAR;

        #pragma unroll
        for (int m = 0; m < 4; ++m) { a47k0[m] = RDA(0, 4 + m, 0); a47k1[m] = RDA(0, 4 + m, 1); }
        STAGE(Bbp, 32768, 0, kt2);
        BAR; LGKM0; PRIO1; MF16(a47k0, b0, 4); PRIO0; BAR;

        STAGE(Ab, 0, 0, kt2);
        BAR; PRIO1; MF16(a47k1, b1, 4); PRIO0; VM4; BAR;

        // ===== tile t+1 (buf1) =====
        #pragma unroll
        for (int m = 0; m < 4; ++m) a0[m] = RDA(1, m, 0);
        #pragma unroll
        for (int n = 0; n < 4; ++n) b0[n] = RDB(1, n, 0);
        STAGE(Ab, 0, 1, kt2);
        BAR; LGKM0; PRIO1; MF16(a0, b0, 0); PRIO0; BAR;

        #pragma unroll
        for (int m = 0; m < 4; ++m) a0[m] = RDA(1, m, 1);
        #pragma unroll
        for (int n = 0; n < 4; ++n) b1[n] = RDB(1, n, 1);
        STAGE(Bbp, 32768, 1, kt2);
        BAR; LGKM0; PRIO1; MF16(a0, b1, 0); PRIO0; BAR;

        #pragma unroll
        for (int m = 0; m < 4; ++m) { a47k0[m] = RDA(1, 4 + m, 0); a47k1[m] = RDA(1, 4 + m, 1); }
        STAGE(Bbp, 65536 + 32768, 0, kt3);
        BAR; LGKM0; PRIO1; MF16(a47k0, b0, 4); PRIO0; BAR;

        STAGE(Ab, 65536, 0, kt3);
        BAR; PRIO1; MF16(a47k1, b1, 4); PRIO0; VM4; BAR;
    }

    if (EPI == 1) {
        #pragma unroll
        for (int fm = 0; fm < 8; ++fm) {
            const int row0 = tileM + wr * 128 + fm * 16 + kq * 4;
            #pragma unroll
            for (int fn = 0; fn < 4; ++fn) {
                const int col = tileN + wc * 64 + fn * 16 + fr;
                #pragma unroll
                for (int r = 0; r < 4; ++r) {
                    float v = acc[fm][fn][r];
                    v = (v > 0.f) ? v : expm1f(v);
                    Cf[(size_t)(row0 + r) * FF + col] = v;
                }
            }
        }
    } else {
        VM0; BAR;
        char* wlds = lds + wid * 16384;
        #pragma unroll
        for (int fm = 0; fm < 8; ++fm)
            #pragma unroll
            for (int fn = 0; fn < 4; ++fn) {
                const int ccol = fn * 16 + fr;
                const int crow = fm * 16 + kq * 4;
                int addr = (ccol * 256 + crow * 2) ^ ((ccol & 7) << 4);
                bf16x4 v = { (__bf16)acc[fm][fn][0], (__bf16)acc[fm][fn][1],
                             (__bf16)acc[fm][fn][2], (__bf16)acc[fm][fn][3] };
                *(bf16x4*)(wlds + addr) = v;
            }
        const int jb = (tileM & 1023) + wr * 128;
        __bf16* Wt = Ct + (size_t)batch * (1024 * 1024);
        #pragma unroll
        for (int pass = 0; pass < 16; ++pass) {
            const int fl  = pass * 4 + (lane >> 4);
            const int jby = (lane & 15) * 16;
            int addr = (fl * 256 + jby) ^ ((fl & 7) << 4);
            bf16x8 v = *(const bf16x8*)(wlds + addr);
            const int fg = tileN + wc * 64 + fl;
            *(bf16x8*)((char*)(Wt + (size_t)fg * 1024 + jb) + jby) = v;
        }
    }
#undef STAGE
#undef RD
#undef RDA
#undef RDB
#undef MF16
}

// ---------------------------------------------------------------------------
// scores_h: wave-per-row. Emits h_bf (nt) + d0..d3.
// ---------------------------------------------------------------------------
__global__ __launch_bounds__(256) void scores_h(
    const float* __restrict__ h, const float* __restrict__ wa,
    __bf16* __restrict__ h_bf,
    float* __restrict__ sSrcSS, float* __restrict__ pD1,
    float* __restrict__ sSrcDS, float* __restrict__ pD3)
{
    const int wid = threadIdx.x >> 6, lane = threadIdx.x & 63;
    const int row = blockIdx.x * 4 + wid;
    const f32x4* hr  = (const f32x4*)(h + (size_t)row * FF);
    const f32x4* w0p = (const f32x4*)wa;
    const f32x4* w1p = (const f32x4*)(wa + FF);
    const f32x4* w2p = (const f32x4*)(wa + 2 * FF);
    const f32x4* w3p = (const f32x4*)(wa + 3 * FF);

    f32x4 hv[4], w0[4], w1[4], w2[4], w3[4];
    #pragma unroll
    for (int q = 0; q < 4; ++q) hv[q] = hr[q * 64 + lane];
    #pragma unroll
    for (int q = 0; q < 4; ++q) {
        const int i = q * 64 + lane;
        w0[q] = w0p[i]; w1[q] = w1p[i]; w2[q] = w2p[i]; w3[q] = w3p[i];
    }

    bf16x4* hbp = (bf16x4*)(h_bf + (size_t)row * FF);
    #pragma unroll
    for (int q = 0; q < 4; ++q) {
        f32x4 v = hv[q];
        bf16x4 hb = { (__bf16)v.x, (__bf16)v.y, (__bf16)v.z, (__bf16)v.w };
        nt_store64(&hbp[q * 64 + lane], &hb);
    }

    float d0 = 0.f, d1 = 0.f, d2 = 0.f, d3 = 0.f;
    #pragma unroll
    for (int q = 0; q < 4; ++q) {
        d0 += dot4(hv[q], w0[q]);
        d1 += dot4(hv[q], w1[q]);
        d2 += dot4(hv[q], w2[q]);
        d3 += dot4(hv[q], w3[q]);
    }
    d0 = waveAllSum(d0); d1 = waveAllSum(d1);
    d2 = waveAllSum(d2); d3 = waveAllSum(d3);
    if (lane == 0) {
        sSrcSS[row] = d0;
        pD1[row]    = d1;
        sSrcDS[row] = d2;
        pD3[row]    = d3;
    }
}

// ---------------------------------------------------------------------------
// scores_react: wave-per-row. Emits d4 (hx.vSS), d5 (ho.vDS).
// ---------------------------------------------------------------------------
__global__ __launch_bounds__(256) void scores_react(
    const float* __restrict__ hx, const float* __restrict__ ho,
    const float* __restrict__ vSS, const float* __restrict__ vDS,
    float* __restrict__ pD4, float* __restrict__ pD5)
{
    const int wid = threadIdx.x >> 6, lane = threadIdx.x & 63;
    const int row = blockIdx.x * 4 + wid;
    const f32x4* xr  = (const f32x4*)(hx + (size_t)row * FF);
    const f32x4* orr = (const f32x4*)(ho + (size_t)row * FF);
    const f32x4* vsp = (const f32x4*)vSS;
    const f32x4* vdp = (const f32x4*)vDS;

    f32x4 xv[4], ov[4], vs[4], vd[4];
    #pragma unroll
    for (int q = 0; q < 4; ++q) {
        const int i = q * 64 + lane;
        xv[q] = xr[i]; ov[q] = orr[i];
    }
    #pragma unroll
    for (int q = 0; q < 4; ++q) {
        const int i = q * 64 + lane;
        vs[q] = vsp[i]; vd[q] = vdp[i];
    }

    float d4 = 0.f, d5 = 0.f;
    #pragma unroll
    for (int q = 0; q < 4; ++q) {
        d4 += dot4(xv[q], vs[q]);
        d5 += dot4(ov[q], vd[q]);
    }
    d4 = waveAllSum(d4); d5 = waveAllSum(d5);
    if (lane == 0) {
        pD4[row] = d4;
        pD5[row] = d5;
    }
}

// Transpose + convert: in [R][C] fp32 -> out [C][R] bf16 (W only), nt stores.
__global__ __launch_bounds__(256) void transpose_cvt(
    const float* __restrict__ in, __bf16* __restrict__ out, int R, int C)
{
    const float* ib = in;
    __bf16* ob = out;
    const int r0 = blockIdx.y * 64;
    const int c0 = blockIdx.x * 64;
    __shared__ __bf16 t[64][66];
    #pragma unroll
    for (int it = 0; it < 16; ++it) {
        int idx = threadIdx.x + it * 256;
        int r = idx >> 6, c = idx & 63;
        t[r][c] = (__bf16)ib[(size_t)(r0 + r) * C + c0 + c];
    }
    __syncthreads();
    #pragma unroll
    for (int it = 0; it < 4; ++it) {
        int idx = threadIdx.x + it * 256;
        int rr = idx >> 4;
        int cc = (idx & 15) * 4;
        bf16x4 v = { t[cc][rr], t[cc + 1][rr], t[cc + 2][rr], t[cc + 3][rr] };
        nt_store64(&ob[(size_t)(c0 + rr) * R + r0 + cc], &v);
    }
}

// wa[q][i]: wa_q = W @ a_q (row dots).
__global__ __launch_bounds__(256) void prep_wa(
    const float* __restrict__ W, const float* __restrict__ aSS,
    const float* __restrict__ aDS, float* __restrict__ wa)
{
    const int i = blockIdx.x;
    const int t = threadIdx.x;
    float4 w  = ((const float4*)(W + (size_t)i * FF))[t];
    float4 s1 = ((const float4*)aSS)[t];
    float4 s2 = ((const float4*)(aSS + FF))[t];
    float4 d1 = ((const float4*)aDS)[t];
    float4 d2 = ((const float4*)(aDS + FF))[t];
    float v0 = w.x * s1.x + w.y * s1.y + w.z * s1.z + w.w * s1.w;
    float v1 = w.x * s2.x + w.y * s2.y + w.z * s2.z + w.w * s2.w;
    float v2 = w.x * d1.x + w.y * d1.y + w.z * d1.z + w.w * d1.w;
    float v3 = w.x * d2.x + w.y * d2.y + w.z * d2.z + w.w * d2.w;
    v0 = waveReduceSum(v0); v1 = waveReduceSum(v1);
    v2 = waveReduceSum(v2); v3 = waveReduceSum(v3);
    __shared__ float red[4][4];
    int wid = t >> 6;
    if ((t & 63) == 0) { red[wid][0] = v0; red[wid][1] = v1; red[wid][2] = v2; red[wid][3] = v3; }
    __syncthreads();
    if (t < 4) {
        float s = red[0][t] + red[1][t] + red[2][t] + red[3][t];
        wa[(size_t)t * FF + i] = s;
    }
}

// v = csk_W^T @ a2 for SS and DS.
__global__ __launch_bounds__(256) void prep_v(
    const float* __restrict__ cskW, const float* __restrict__ aSS,
    const float* __restrict__ aDS, float* __restrict__ vSS, float* __restrict__ vDS)
{
    const int g0 = blockIdx.x * 64;
    const int gl = threadIdx.x & 63;
    const int fs = threadIdx.x >> 6;
    const int g = g0 + gl;
    float aS = 0.f, aD = 0.f;
    for (int f = fs * 256; f < fs * 256 + 256; ++f) {
        float w = cskW[(size_t)f * FF + g];
        aS += w * aSS[FF + f];
        aD += w * aDS[FF + f];
    }
    __shared__ float rS[4][64], rD[4][64];
    rS[fs][gl] = aS; rD[fs][gl] = aD;
    __syncthreads();
    if (fs == 0) {
        vSS[g] = rS[0][gl] + rS[1][gl] + rS[2][gl] + rS[3][gl];
        vDS[g] = rD[0][gl] + rD[1][gl] + rD[2][gl] + rD[3][gl];
    }
}

__global__ __launch_bounds__(256) void prep_c(
    const float* __restrict__ cskb, const float* __restrict__ aSS,
    const float* __restrict__ aDS, float* __restrict__ cv)
{
    int t = threadIdx.x;
    float cS = 0.f, cD = 0.f;
    for (int f = t; f < FF; f += 256) {
        float bb = cskb[f];
        cS += bb * aSS[FF + f];
        cD += bb * aDS[FF + f];
    }
    cS = waveReduceSum(cS);
    cD = waveReduceSum(cD);
    __shared__ float rA[4], rB[4];
    int wid = t >> 6;
    if ((t & 63) == 0) { rA[wid] = cS; rB[wid] = cD; }
    __syncthreads();
    if (t == 0) {
        cv[0] = rA[0] + rA[1] + rA[2] + rA[3];
        cv[1] = rB[0] + rB[1] + rB[2] + rB[3];
    }
}

// ---------------------------------------------------------------------------
// Row softmax -> att (bf16, nt stores), wave-per-row.
// ---------------------------------------------------------------------------
__global__ __launch_bounds__(256) void softmax_att(
    const float* __restrict__ mx, const float* __restrict__ mo,
    const float* __restrict__ sSrcSS, const float* __restrict__ sSrcDS,
    const float* __restrict__ pD1, const float* __restrict__ pD3,
    const float* __restrict__ pD4, const float* __restrict__ pD5,
    const float* __restrict__ cv, __bf16* __restrict__ att)
{
    const int wid = threadIdx.x >> 6, lane = threadIdx.x & 63;
    const int row = blockIdx.x * 4 + wid;
    const int base = row & ~(NN - 1);
    const float srcS = sSrcSS[row];
    const float srcD = sSrcDS[row];
    const float cv0 = cv[0], cv1 = cv[1];
    const f32x4* mxr = (const f32x4*)(mx + (size_t)row * NN);
    const f32x4* mor = (const f32x4*)(mo + (size_t)row * NN);
    const f32x4* p1p = (const f32x4*)(pD1 + base);
    const f32x4* p3p = (const f32x4*)(pD3 + base);
    const f32x4* p4p = (const f32x4*)(pD4 + base);
    const f32x4* p5p = (const f32x4*)(pD5 + base);

    float ev[16];
    float m = -INFINITY;
    #pragma unroll
    for (int q = 0; q < 4; ++q) {
        const int idx = q * 64 + lane;
        f32x4 a = mxr[idx], o = mor[idx];
        f32x4 p1 = p1p[idx], p3 = p3p[idx], p4 = p4p[idx], p5 = p5p[idx];
        #pragma unroll
        for (int l = 0; l < 4; ++l) {
            float eS = srcS + p1[l] + p4[l] + cv0;
            float lS = (eS >= 0.f) ? eS : ALPHA * eS;
            float eD = srcD + p3[l] + p5[l] + cv1;
            float lD = (eD >= 0.f) ? eD : ALPHA * eD;
            float val = (a[l] > 0.f) ? (lS * a[l] + lD * o[l]) : NEG_INF;
            ev[q * 4 + l] = val;
            m = fmaxf(m, val);
        }
    }
    m = waveAllMax(m);

    float s = 0.f;
    #pragma unroll
    for (int i = 0; i < 16; ++i) {
        float p = expf(ev[i] - m);
        ev[i] = p;
        s += p;
    }
    s = waveAllSum(s);
    const float inv = 1.f / s;

    bf16x4* ar = (bf16x4*)(att + (size_t)row * NN);
    #pragma unroll
    for (int q = 0; q < 4; ++q) {
        bf16x4 v = { (__bf16)(ev[q * 4 + 0] * inv), (__bf16)(ev[q * 4 + 1] * inv),
                     (__bf16)(ev[q * 4 + 2] * inv), (__bf16)(ev[q * 4 + 3] * inv) };
        nt_store64(&ar[q * 64 + lane], &v);
    }
}

// ---------------------------------------------------------------------------
extern "C" void kernel_launch(void* const* d_in, const int* in_sizes, int n_in,
                              void* d_out, int out_size, void* d_ws, size_t ws_size,
                              hipStream_t stream)
{
    const float* h    = (const float*)d_in[0];
    const float* hx   = (const float*)d_in[1];
    const float* ho   = (const float*)d_in[2];
    const float* mx   = (const float*)d_in[3];
    const float* mo   = (const float*)d_in[4];
    const float* W    = (const float*)d_in[5];
    const float* aSS  = (const float*)d_in[6];
    const float* aDS  = (const float*)d_in[7];
    const float* cskW = (const float*)d_in[8];
    const float* cskb = (const float*)d_in[9];
    float* out = (float*)d_out;

    char* ws = (char*)d_ws;
    const size_t MB = 1024 * 1024;
    __bf16* h_bf   = (__bf16*)ws;              // 32MB
    __bf16* WhT_bf = (__bf16*)(ws + 32 * MB);  // 32MB (per-batch [F][N] bf16)
    __bf16* att_bf = (__bf16*)(ws + 64 * MB);  // 32MB
    __bf16* WbfT   = (__bf16*)(ws + 96 * MB);  // 2MB
    float* wa     = (float*)(ws + 98 * MB);    // 16KB [4][FF]
    float* vSS    = wa + 4 * FF;
    float* vDS    = vSS + FF;
    float* cv     = vDS + FF;
    float* sSrcSS = cv + 64;
    float* sSrcDS = sSrcSS + BZ * NN;
    float* pD1    = sSrcDS + BZ * NN;
    float* pD3    = pD1 + BZ * NN;
    float* pD4    = pD3 + BZ * NN;
    float* pD5    = pD4 + BZ * NN;

    // 1) small prep (fp32)
    prep_wa<<<FF, 256, 0, stream>>>(W, aSS, aDS, wa);
    prep_v<<<16, 256, 0, stream>>>(cskW, aSS, aDS, vSS, vDS);
    prep_c<<<1, 256, 0, stream>>>(cskb, aSS, aDS, cv);
    // 2) W -> W^T bf16
    transpose_cvt<<<dim3(16, 16, 1), 256, 0, stream>>>(W, WbfT, FF, FF);
    // 3) score passes (stream-split, load-hoisted, nt outputs)
    scores_h<<<BZ * NN / 4, 256, 0, stream>>>(h, wa, h_bf, sSrcSS, pD1, sSrcDS, pD3);
    scores_react<<<BZ * NN / 4, 256, 0, stream>>>(hx, ho, vSS, vDS, pD4, pD5);
    // 4) Wh^T bf16 = (h @ W)^T per batch (R6 schedule, plain stores)
    gemm256<2><<<256, 512, 0, stream>>>(h_bf, WbfT, nullptr, WhT_bf, 0);
    // 5) softmax -> att bf16 (nt)
    softmax_att<<<BZ * NN / 4, 256, 0, stream>>>(mx, mo, sSrcSS, sSrcDS,
                                                 pD1, pD3, pD4, pD5, cv, att_bf);
    // 6) out = elu(att @ Wh)
    gemm256<1><<<256, 512, 0, stream>>>(att_bf, WhT_bf, out, nullptr,
                                        (size_t)NN * FF);
}

// Round 10
// 193.670 us; speedup vs baseline: 1.0890x; 1.0636x over previous
//
#include <hip/hip_runtime.h>
#include <hip/hip_bf16.h>
#include <math.h>

#define BZ 16
#define NN 1024
#define FF 1024
#define ALPHA 0.2f
#define NEG_INF (-9e15f)

typedef __bf16 bf16x8 __attribute__((ext_vector_type(8)));
typedef __bf16 bf16x4 __attribute__((ext_vector_type(4)));
typedef float  f32x4  __attribute__((ext_vector_type(4)));

#define GLOBAL_AS __attribute__((address_space(1)))
#define LDS_AS    __attribute__((address_space(3)))

__device__ inline void load_lds16(const void* g, void* l) {
    __builtin_amdgcn_global_load_lds((const GLOBAL_AS void*)g, (LDS_AS void*)l, 16, 0, 0);
}

// nt stores only on streaming producer outputs (R7 evidence).
__device__ inline void nt_store64(void* p, const void* v) {
    __builtin_nontemporal_store(*(const unsigned long long*)v, (unsigned long long*)p);
}

__device__ inline float waveAllSum(float v) {
    for (int o = 32; o; o >>= 1) v += __shfl_xor(v, o);
    return v;
}
__device__ inline float waveAllMax(float v) {
    for (int o = 32; o; o >>= 1) v = fmaxf(v, __shfl_xor(v, o));
    return v;
}
__device__ inline float waveReduceSum(float v) {
    for (int o = 32; o; o >>= 1) v += __shfl_down(v, o);
    return v;
}
__device__ inline float dot4(f32x4 a, f32x4 b) {
    return a.x * b.x + a.y * b.y + a.z * b.z + a.w * b.w;
}

// ===========================================================================
// 256x256 bf16 MFMA GEMM — R6/R9 proven schedule (BK=64, 2 dbuf, 4 phases
// per K-tile, K-half split, st-swizzled LDS, counted vmcnt(4)). FROZEN.
// ===========================================================================
template<int EPI>
__global__ __launch_bounds__(512, 2) void gemm256(
    const __bf16* __restrict__ A, const __bf16* __restrict__ Bt,
    float* __restrict__ Cf, __bf16* __restrict__ Ct, size_t sB)
{
    __shared__ char lds[131072];

    const int bid = blockIdx.x;
    const int l   = (bid & 7) * 32 + (bid >> 3);
    const int tileM = (l >> 2) * 256;
    const int tileN = (l & 3) * 256;

    const int tid = threadIdx.x, lane = tid & 63, wid = tid >> 6;
    const int wr = wid >> 2, wc = wid & 3;

    const int batch = tileM >> 10;
    const char* Ab  = (const char*)(A + (size_t)tileM * FF);
    const char* Bbp = (const char*)(Bt + (size_t)batch * sB + (size_t)tileN * FF);

    const int o1 = wid * 1024 + lane * 16;
    const int o2 = o1 + 8192;
    const int r1 = o1 >> 7, r2 = o2 >> 7;
    const size_t raoff1 = (size_t)r1 * 2048 + ((o1 & 127) ^ ((r1 & 7) << 4));
    const size_t raoff2 = (size_t)r2 * 2048 + ((o2 & 127) ^ ((r2 & 7) << 4));

#define STAGE(gb, ldsoff, half, kt) do {                                        \
    const char* g_ = (gb) + (size_t)(half) * (128 * 2048) + (size_t)(kt) * 128; \
    load_lds16(g_ + raoff1, lds + (ldsoff) + (half) * 16384 + wid * 1024);      \
    load_lds16(g_ + raoff2, lds + (ldsoff) + (half) * 16384 + 8192 + wid * 1024);\
} while (0)

    const int fr = lane & 15, kq = lane >> 4;
    const int fswz = (fr & 7) << 4;
    const int ck[2] = { (kq * 16) ^ fswz, (64 + kq * 16) ^ fswz };
    const int abase = (wr * 128 + fr) * 128;
    const int bbase = 32768 + (wc * 64 + fr) * 128;

#define RD(off) (*(const bf16x8*)(lds + (off)))
#define RDA(P, m, kh) RD((P) * 65536 + abase + (m) * 2048 + ck[kh])
#define RDB(P, n, kh) RD((P) * 65536 + bbase + (n) * 2048 + ck[kh])
#define MF16(amr, bvr, m0) do {                                              \
    _Pragma("unroll") for (int n = 0; n < 4; ++n)                            \
    _Pragma("unroll") for (int m = 0; m < 4; ++m)                            \
        acc[m0 + m][n] = __builtin_amdgcn_mfma_f32_16x16x32_bf16(            \
            amr[m], bvr[n], acc[m0 + m][n], 0, 0, 0); } while (0)
#define BAR   __builtin_amdgcn_s_barrier()
#define LGKM0 do { asm volatile("s_waitcnt lgkmcnt(0)" ::: "memory");        \
                   __builtin_amdgcn_sched_barrier(0); } while (0)
#define VM4   asm volatile("s_waitcnt vmcnt(4)" ::: "memory")
#define VM0   asm volatile("s_waitcnt vmcnt(0)" ::: "memory")
#define PRIO1 __builtin_amdgcn_s_setprio(1)
#define PRIO0 __builtin_amdgcn_s_setprio(0)

    f32x4 acc[8][4];
    #pragma unroll
    for (int m = 0; m < 8; ++m)
        #pragma unroll
        for (int n = 0; n < 4; ++n) acc[m][n] = (f32x4){0.f, 0.f, 0.f, 0.f};

    bf16x8 a0[4], a47k0[4], a47k1[4], b0[4], b1[4];

    STAGE(Ab,      0, 0, 0);  STAGE(Ab,      0, 1, 0);
    STAGE(Bbp, 32768, 0, 0);  STAGE(Bbp, 32768, 1, 0);
    STAGE(Bbp, 65536 + 32768, 0, 1);
    STAGE(Ab,  65536,         0, 1);
    VM4; BAR;

    const int NT = FF / 64;   // 16
    for (int it = 0; it < NT / 2; ++it) {
        const int t   = 2 * it;
        const int kt1 = t + 1;
        const int kt2 = (t + 2 < NT) ? t + 2 : NT - 1;
        const int kt3 = (t + 3 < NT) ? t + 3 : NT - 1;

        #pragma unroll
        for (int m = 0; m < 4; ++m) a0[m] = RDA(0, m, 0);
        #pragma unroll
        for (int n = 0; n < 4; ++n) b0[n] = RDB(0, n, 0);
        STAGE(Ab, 65536, 1, kt1);
        BAR; LGKM0; PRIO1; MF16(a0, b0, 0); PRIO0; BAR;

        #pragma unroll
        for (int m = 0; m < 4; ++m) a0[m] = RDA(0, m, 1);
        #pragma unroll
        for (int n = 0; n < 4; ++n) b1[n] = RDB(0, n, 1);
        STAGE(Bbp, 65536 + 32768, 1, kt1);
        BAR; LGKM0; PRIO1; MF16(a0, b1, 0); PRIO0; BAR;

        #pragma unroll
        for (int m = 0; m < 4; ++m) { a47k0[m] = RDA(0, 4 + m, 0); a47k1[m] = RDA(0, 4 + m, 1); }
        STAGE(Bbp, 32768, 0, kt2);
        BAR; LGKM0; PRIO1; MF16(a47k0, b0, 4); PRIO0; BAR;

        STAGE(Ab, 0, 0, kt2);
        BAR; PRIO1; MF16(a47k1, b1, 4); PRIO0; VM4; BAR;

        #pragma unroll
        for (int m = 0; m < 4; ++m) a0[m] = RDA(1, m, 0);
        #pragma unroll
        for (int n = 0; n < 4; ++n) b0[n] = RDB(1, n, 0);
        STAGE(Ab, 0, 1, kt2);
        BAR; LGKM0; PRIO1; MF16(a0, b0, 0); PRIO0; BAR;

        #pragma unroll
        for (int m = 0; m < 4; ++m) a0[m] = RDA(1, m, 1);
        #pragma unroll
        for (int n = 0; n < 4; ++n) b1[n] = RDB(1, n, 1);
        STAGE(Bbp, 32768, 1, kt2);
        BAR; LGKM0; PRIO1; MF16(a0, b1, 0); PRIO0; BAR;

        #pragma unroll
        for (int m = 0; m < 4; ++m) { a47k0[m] = RDA(1, 4 + m, 0); a47k1[m] = RDA(1, 4 + m, 1); }
        STAGE(Bbp, 65536 + 32768, 0, kt3);
        BAR; LGKM0; PRIO1; MF16(a47k0, b0, 4); PRIO0; BAR;

        STAGE(Ab, 65536, 0, kt3);
        BAR; PRIO1; MF16(a47k1, b1, 4); PRIO0; VM4; BAR;
    }

    if (EPI == 1) {
        #pragma unroll
        for (int fm = 0; fm < 8; ++fm) {
            const int row0 = tileM + wr * 128 + fm * 16 + kq * 4;
            #pragma unroll
            for (int fn = 0; fn < 4; ++fn) {
                const int col = tileN + wc * 64 + fn * 16 + fr;
                #pragma unroll
                for (int r = 0; r < 4; ++r) {
                    float v = acc[fm][fn][r];
                    v = (v > 0.f) ? v : expm1f(v);
                    Cf[(size_t)(row0 + r) * FF + col] = v;
                }
            }
        }
    } else {
        VM0; BAR;
        char* wlds = lds + wid * 16384;
        #pragma unroll
        for (int fm = 0; fm < 8; ++fm)
            #pragma unroll
            for (int fn = 0; fn < 4; ++fn) {
                const int ccol = fn * 16 + fr;
                const int crow = fm * 16 + kq * 4;
                int addr = (ccol * 256 + crow * 2) ^ ((ccol & 7) << 4);
                bf16x4 v = { (__bf16)acc[fm][fn][0], (__bf16)acc[fm][fn][1],
                             (__bf16)acc[fm][fn][2], (__bf16)acc[fm][fn][3] };
                *(bf16x4*)(wlds + addr) = v;
            }
        const int jb = (tileM & 1023) + wr * 128;
        __bf16* Wt = Ct + (size_t)batch * (1024 * 1024);
        #pragma unroll
        for (int pass = 0; pass < 16; ++pass) {
            const int fl  = pass * 4 + (lane >> 4);
            const int jby = (lane & 15) * 16;
            int addr = (fl * 256 + jby) ^ ((fl & 7) << 4);
            bf16x8 v = *(const bf16x8*)(wlds + addr);
            const int fg = tileN + wc * 64 + fl;
            *(bf16x8*)((char*)(Wt + (size_t)fg * 1024 + jb) + jby) = v;
        }
    }
#undef STAGE
#undef RD
#undef RDA
#undef RDB
#undef MF16
}

// ===========================================================================
// prep_all: all small prep work in ONE dispatch (independent block ranges).
//   blocks [0,1024):    wa[q][i] = W-row(i) . a_q
//   blocks [1024,1040): vSS/vDS = csk_W^T @ a2 (64 cols per block)
//   block  1040:        cv = csk_b . a2
//   blocks [1041,1297): W -> W^T bf16 transpose tiles (16x16 grid of 64x64)
// ===========================================================================
__global__ __launch_bounds__(256) void prep_all(
    const float* __restrict__ W, const float* __restrict__ aSS,
    const float* __restrict__ aDS, const float* __restrict__ cskW,
    const float* __restrict__ cskb,
    float* __restrict__ wa, float* __restrict__ vSS, float* __restrict__ vDS,
    float* __restrict__ cv, __bf16* __restrict__ WbfT)
{
    __shared__ char smem[64 * 66 * 2];   // max of all sections (transpose tile)
    const int bid = blockIdx.x;
    const int t = threadIdx.x;

    if (bid < 1024) {
        // ---- prep_wa: row i = bid ----
        const int i = bid;
        float4 w  = ((const float4*)(W + (size_t)i * FF))[t];
        float4 s1 = ((const float4*)aSS)[t];
        float4 s2 = ((const float4*)(aSS + FF))[t];
        float4 d1 = ((const float4*)aDS)[t];
        float4 d2 = ((const float4*)(aDS + FF))[t];
        float v0 = w.x * s1.x + w.y * s1.y + w.z * s1.z + w.w * s1.w;
        float v1 = w.x * s2.x + w.y * s2.y + w.z * s2.z + w.w * s2.w;
        float v2 = w.x * d1.x + w.y * d1.y + w.z * d1.z + w.w * d1.w;
        float v3 = w.x * d2.x + w.y * d2.y + w.z * d2.z + w.w * d2.w;
        v0 = waveReduceSum(v0); v1 = waveReduceSum(v1);
        v2 = waveReduceSum(v2); v3 = waveReduceSum(v3);
        float (*red)[4] = (float (*)[4])smem;
        int wid = t >> 6;
        if ((t & 63) == 0) { red[wid][0] = v0; red[wid][1] = v1; red[wid][2] = v2; red[wid][3] = v3; }
        __syncthreads();
        if (t < 4) {
            float s = red[0][t] + red[1][t] + red[2][t] + red[3][t];
            wa[(size_t)t * FF + i] = s;
        }
    } else if (bid < 1040) {
        // ---- prep_v: cols g0..g0+63 ----
        const int g0 = (bid - 1024) * 64;
        const int gl = t & 63;
        const int fs = t >> 6;
        const int g = g0 + gl;
        float aS = 0.f, aD = 0.f;
        for (int f = fs * 256; f < fs * 256 + 256; ++f) {
            float w = cskW[(size_t)f * FF + g];
            aS += w * aSS[FF + f];
            aD += w * aDS[FF + f];
        }
        float (*rS)[64] = (float (*)[64])smem;
        float (*rD)[64] = (float (*)[64])(smem + 4 * 64 * 4);
        rS[fs][gl] = aS; rD[fs][gl] = aD;
        __syncthreads();
        if (fs == 0) {
            vSS[g] = rS[0][gl] + rS[1][gl] + rS[2][gl] + rS[3][gl];
            vDS[g] = rD[0][gl] + rD[1][gl] + rD[2][gl] + rD[3][gl];
        }
    } else if (bid == 1040) {
        // ---- prep_c ----
        float cS = 0.f, cD = 0.f;
        for (int f = t; f < FF; f += 256) {
            float bb = cskb[f];
            cS += bb * aSS[FF + f];
            cD += bb * aDS[FF + f];
        }
        cS = waveReduceSum(cS);
        cD = waveReduceSum(cD);
        float* rA = (float*)smem;
        float* rB = (float*)smem + 4;
        int wid = t >> 6;
        if ((t & 63) == 0) { rA[wid] = cS; rB[wid] = cD; }
        __syncthreads();
        if (t == 0) {
            cv[0] = rA[0] + rA[1] + rA[2] + rA[3];
            cv[1] = rB[0] + rB[1] + rB[2] + rB[3];
        }
    } else {
        // ---- transpose_cvt tile: idx = bid-1041 in 16x16 grid ----
        const int idx2 = bid - 1041;
        const int c0 = (idx2 & 15) * 64;
        const int r0 = (idx2 >> 4) * 64;
        __bf16 (*tt)[66] = (__bf16 (*)[66])smem;
        #pragma unroll
        for (int it = 0; it < 16; ++it) {
            int idx = t + it * 256;
            int r = idx >> 6, c = idx & 63;
            tt[r][c] = (__bf16)W[(size_t)(r0 + r) * FF + c0 + c];
        }
        __syncthreads();
        #pragma unroll
        for (int it = 0; it < 4; ++it) {
            int idx = t + it * 256;
            int rr = idx >> 4;
            int cc = (idx & 15) * 4;
            bf16x4 v = { tt[cc][rr], tt[cc + 1][rr], tt[cc + 2][rr], tt[cc + 3][rr] };
            nt_store64(&WbfT[(size_t)(c0 + rr) * FF + r0 + cc], &v);
        }
    }
}

// ===========================================================================
// scores_all: two sequential hoisted phases in one dispatch (wave-per-row).
// Phase 1 (scores_h): reads h + wa -> h_bf (nt) + d0..d3.
// Phase 2 (scores_react): reads hx, ho + v -> d4, d5.
// sched_barrier(0) between phases pins the load hoisting per phase.
// ===========================================================================
__global__ __launch_bounds__(256) void scores_all(
    const float* __restrict__ h, const float* __restrict__ hx,
    const float* __restrict__ ho, const float* __restrict__ wa,
    const float* __restrict__ vSS, const float* __restrict__ vDS,
    __bf16* __restrict__ h_bf,
    float* __restrict__ sSrcSS, float* __restrict__ pD1,
    float* __restrict__ sSrcDS, float* __restrict__ pD3,
    float* __restrict__ pD4, float* __restrict__ pD5)
{
    const int wid = threadIdx.x >> 6, lane = threadIdx.x & 63;
    const int row = blockIdx.x * 4 + wid;

    // ---- phase 1: h-based scores + h->bf16 ----
    {
        const f32x4* hr  = (const f32x4*)(h + (size_t)row * FF);
        const f32x4* w0p = (const f32x4*)wa;
        const f32x4* w1p = (const f32x4*)(wa + FF);
        const f32x4* w2p = (const f32x4*)(wa + 2 * FF);
        const f32x4* w3p = (const f32x4*)(wa + 3 * FF);

        f32x4 hv[4], w0[4], w1[4], w2[4], w3[4];
        #pragma unroll
        for (int q = 0; q < 4; ++q) hv[q] = hr[q * 64 + lane];
        #pragma unroll
        for (int q = 0; q < 4; ++q) {
            const int i = q * 64 + lane;
            w0[q] = w0p[i]; w1[q] = w1p[i]; w2[q] = w2p[i]; w3[q] = w3p[i];
        }

        bf16x4* hbp = (bf16x4*)(h_bf + (size_t)row * FF);
        #pragma unroll
        for (int q = 0; q < 4; ++q) {
            f32x4 v = hv[q];
            bf16x4 hb = { (__bf16)v.x, (__bf16)v.y, (__bf16)v.z, (__bf16)v.w };
            nt_store64(&hbp[q * 64 + lane], &hb);
        }

        float d0 = 0.f, d1 = 0.f, d2 = 0.f, d3 = 0.f;
        #pragma unroll
        for (int q = 0; q < 4; ++q) {
            d0 += dot4(hv[q], w0[q]);
            d1 += dot4(hv[q], w1[q]);
            d2 += dot4(hv[q], w2[q]);
            d3 += dot4(hv[q], w3[q]);
        }
        d0 = waveAllSum(d0); d1 = waveAllSum(d1);
        d2 = waveAllSum(d2); d3 = waveAllSum(d3);
        if (lane == 0) {
            sSrcSS[row] = d0;
            pD1[row]    = d1;
            sSrcDS[row] = d2;
            pD3[row]    = d3;
        }
    }

    __builtin_amdgcn_sched_barrier(0);

    // ---- phase 2: react-based scores ----
    {
        const f32x4* xr  = (const f32x4*)(hx + (size_t)row * FF);
        const f32x4* orr = (const f32x4*)(ho + (size_t)row * FF);
        const f32x4* vsp = (const f32x4*)vSS;
        const f32x4* vdp = (const f32x4*)vDS;

        f32x4 xv[4], ov[4], vs[4], vd[4];
        #pragma unroll
        for (int q = 0; q < 4; ++q) {
            const int i = q * 64 + lane;
            xv[q] = xr[i]; ov[q] = orr[i];
        }
        #pragma unroll
        for (int q = 0; q < 4; ++q) {
            const int i = q * 64 + lane;
            vs[q] = vsp[i]; vd[q] = vdp[i];
        }

        float d4 = 0.f, d5 = 0.f;
        #pragma unroll
        for (int q = 0; q < 4; ++q) {
            d4 += dot4(xv[q], vs[q]);
            d5 += dot4(ov[q], vd[q]);
        }
        d4 = waveAllSum(d4); d5 = waveAllSum(d5);
        if (lane == 0) {
            pD4[row] = d4;
            pD5[row] = d5;
        }
    }
}

// ---------------------------------------------------------------------------
// Row softmax -> att (bf16, nt stores), wave-per-row. FROZEN from R9.
// ---------------------------------------------------------------------------
__global__ __launch_bounds__(256) void softmax_att(
    const float* __restrict__ mx, const float* __restrict__ mo,
    const float* __restrict__ sSrcSS, const float* __restrict__ sSrcDS,
    const float* __restrict__ pD1, const float* __restrict__ pD3,
    const float* __restrict__ pD4, const float* __restrict__ pD5,
    const float* __restrict__ cv, __bf16* __restrict__ att)
{
    const int wid = threadIdx.x >> 6, lane = threadIdx.x & 63;
    const int row = blockIdx.x * 4 + wid;
    const int base = row & ~(NN - 1);
    const float srcS = sSrcSS[row];
    const float srcD = sSrcDS[row];
    const float cv0 = cv[0], cv1 = cv[1];
    const f32x4* mxr = (const f32x4*)(mx + (size_t)row * NN);
    const f32x4* mor = (const f32x4*)(mo + (size_t)row * NN);
    const f32x4* p1p = (const f32x4*)(pD1 + base);
    const f32x4* p3p = (const f32x4*)(pD3 + base);
    const f32x4* p4p = (const f32x4*)(pD4 + base);
    const f32x4* p5p = (const f32x4*)(pD5 + base);

    float ev[16];
    float m = -INFINITY;
    #pragma unroll
    for (int q = 0; q < 4; ++q) {
        const int idx = q * 64 + lane;
        f32x4 a = mxr[idx], o = mor[idx];
        f32x4 p1 = p1p[idx], p3 = p3p[idx], p4 = p4p[idx], p5 = p5p[idx];
        #pragma unroll
        for (int l = 0; l < 4; ++l) {
            float eS = srcS + p1[l] + p4[l] + cv0;
            float lS = (eS >= 0.f) ? eS : ALPHA * eS;
            float eD = srcD + p3[l] + p5[l] + cv1;
            float lD = (eD >= 0.f) ? eD : ALPHA * eD;
            float val = (a[l] > 0.f) ? (lS * a[l] + lD * o[l]) : NEG_INF;
            ev[q * 4 + l] = val;
            m = fmaxf(m, val);
        }
    }
    m = waveAllMax(m);

    float s = 0.f;
    #pragma unroll
    for (int i = 0; i < 16; ++i) {
        float p = expf(ev[i] - m);
        ev[i] = p;
        s += p;
    }
    s = waveAllSum(s);
    const float inv = 1.f / s;

    bf16x4* ar = (bf16x4*)(att + (size_t)row * NN);
    #pragma unroll
    for (int q = 0; q < 4; ++q) {
        bf16x4 v = { (__bf16)(ev[q * 4 + 0] * inv), (__bf16)(ev[q * 4 + 1] * inv),
                     (__bf16)(ev[q * 4 + 2] * inv), (__bf16)(ev[q * 4 + 3] * inv) };
        nt_store64(&ar[q * 64 + lane], &v);
    }
}

// ---------------------------------------------------------------------------
extern "C" void kernel_launch(void* const* d_in, const int* in_sizes, int n_in,
                              void* d_out, int out_size, void* d_ws, size_t ws_size,
                              hipStream_t stream)
{
    const float* h    = (const float*)d_in[0];
    const float* hx   = (const float*)d_in[1];
    const float* ho   = (const float*)d_in[2];
    const float* mx   = (const float*)d_in[3];
    const float* mo   = (const float*)d_in[4];
    const float* W    = (const float*)d_in[5];
    const float* aSS  = (const float*)d_in[6];
    const float* aDS  = (const float*)d_in[7];
    const float* cskW = (const float*)d_in[8];
    const float* cskb = (const float*)d_in[9];
    float* out = (float*)d_out;

    char* ws = (char*)d_ws;
    const size_t MB = 1024 * 1024;
    __bf16* h_bf   = (__bf16*)ws;              // 32MB
    __bf16* WhT_bf = (__bf16*)(ws + 32 * MB);  // 32MB (per-batch [F][N] bf16)
    __bf16* att_bf = (__bf16*)(ws + 64 * MB);  // 32MB
    __bf16* WbfT   = (__bf16*)(ws + 96 * MB);  // 2MB
    float* wa     = (float*)(ws + 98 * MB);    // 16KB [4][FF]
    float* vSS    = wa + 4 * FF;
    float* vDS    = vSS + FF;
    float* cv     = vDS + FF;
    float* sSrcSS = cv + 64;
    float* sSrcDS = sSrcSS + BZ * NN;
    float* pD1    = sSrcDS + BZ * NN;
    float* pD3    = pD1 + BZ * NN;
    float* pD4    = pD3 + BZ * NN;
    float* pD5    = pD4 + BZ * NN;

    // 1) all prep work in one dispatch
    prep_all<<<1297, 256, 0, stream>>>(W, aSS, aDS, cskW, cskb,
                                       wa, vSS, vDS, cv, WbfT);
    // 2) all score GEMVs + h->bf16 in one dispatch
    scores_all<<<BZ * NN / 4, 256, 0, stream>>>(h, hx, ho, wa, vSS, vDS, h_bf,
                                                sSrcSS, pD1, sSrcDS, pD3,
                                                pD4, pD5);
    // 3) Wh^T bf16 = (h @ W)^T per batch
    gemm256<2><<<256, 512, 0, stream>>>(h_bf, WbfT, nullptr, WhT_bf, 0);
    // 4) softmax -> att bf16
    softmax_att<<<BZ * NN / 4, 256, 0, stream>>>(mx, mo, sSrcSS, sSrcDS,
                                                 pD1, pD3, pD4, pD5, cv, att_bf);
    // 5) out = elu(att @ Wh)
    gemm256<1><<<256, 512, 0, stream>>>(att_bf, WhT_bf, out, nullptr,
                                        (size_t)NN * FF);
}